// Round 7
// baseline (321.523 us; speedup 1.0000x reference)
//
#include <hip/hip_runtime.h>
#include <hip/hip_bf16.h>
#include <stdint.h>

// Problem constants (fixed by reference)
#define TSEQ   2048
#define DMODEL 1024
#define NH     16
#define HDIM   64
#define NKVH   4

typedef __attribute__((ext_vector_type(8))) short short8;
typedef __attribute__((ext_vector_type(8))) _Float16 half8;
typedef __attribute__((ext_vector_type(4))) float f32x4;
typedef __hip_bfloat16 bf16;

// async global->LDS, 16B per lane (linear LDS dest = wave base + lane*16)
__device__ __forceinline__ void gload16(const void* g, void* l) {
    __builtin_amdgcn_global_load_lds(
        (const __attribute__((address_space(1))) uint32_t*)g,
        (__attribute__((address_space(3))) uint32_t*)l, 16, 0, 0);
}

// priority comparator: higher score wins; tie -> lower index wins (matches jax top_k)
__device__ __forceinline__ bool pgt(float as, int ai, float bs, int bi) {
    return (as > bs) || (as == bs && ai < bi);
}

// full bitonic sort across 64 lanes, ascending by priority (validated R6)
__device__ __forceinline__ void bsort(float& s, int& i, int lane) {
#pragma unroll
    for (int k = 2; k <= 64; k <<= 1) {
#pragma unroll
        for (int j = k >> 1; j > 0; j >>= 1) {
            float os = __shfl_xor(s, j, 64);
            int   oi = __shfl_xor(i, j, 64);
            bool lower = (lane & j) == 0;
            bool asc   = (lane & k) == 0;
            bool wmin  = (lower == asc);
            bool takeo = (pgt(s, i, os, oi) == wmin);
            if (takeo) { s = os; i = oi; }
        }
    }
}

// bitonic -> ascending cleanup (6 stages) (validated R6)
__device__ __forceinline__ void bmerge(float& s, int& i, int lane) {
#pragma unroll
    for (int j = 32; j > 0; j >>= 1) {
        float os = __shfl_xor(s, j, 64);
        int   oi = __shfl_xor(i, j, 64);
        bool lower = (lane & j) == 0;
        bool takeo = (pgt(s, i, os, oi) == lower);
        if (takeo) { s = os; i = oi; }
    }
}

// ---- fp32 -> bf16 conversion of x ----
__global__ __launch_bounds__(256) void convert_x(
    const float* __restrict__ x, bf16* __restrict__ cx)
{
    const size_t i0 = (size_t)blockIdx.x * 256 + threadIdx.x;
    const size_t stride = (size_t)gridDim.x * 256;
    for (size_t i = i0; i < 2097152; i += stride) cx[i] = __float2bfloat16(x[i]);
}

// ---- fp32 [R][C] -> bf16 [C][R] tiled transpose-convert (weights, one-shot) ----
__global__ __launch_bounds__(256) void transpose_conv(
    const float* __restrict__ in, bf16* __restrict__ out, int R, int Cc)
{
    __shared__ float tile[32][33];
    const int bx = blockIdx.x * 32;   // col base (n)
    const int by = blockIdx.y * 32;   // row base (k)
    const int tx = threadIdx.x & 31, ty = threadIdx.x >> 5;   // 32 x 8
#pragma unroll
    for (int i = 0; i < 32; i += 8)
        tile[ty + i][tx] = in[(size_t)(by + ty + i) * Cc + bx + tx];
    __syncthreads();
#pragma unroll
    for (int i = 0; i < 32; i += 8)
        out[(size_t)(bx + ty + i) * R + by + tx] = __float2bfloat16(tile[tx][ty + i]);
}

// ---- MFMA GEMM: C[M,N] fp32 = A[M,K](bf16) @ BT[N,K](bf16)^T + bias[N](fp32)
// (unchanged from R4 — validated)
__global__ __launch_bounds__(256) void gemm_bias(
    const bf16* __restrict__ A, const bf16* __restrict__ BT,
    const float* __restrict__ bias, float* __restrict__ C,
    int M, int N, int K)
{
    __shared__ short As[64][64];   // (m, k-slot-swizzled)  8KB
    __shared__ short Bs[64][64];   // (n, k-slot-swizzled)  8KB
    const int tid = threadIdx.x;
    const int m0 = blockIdx.y * 64, n0 = blockIdx.x * 64;
    const int w = tid >> 6, lane = tid & 63;
    const int q4 = lane >> 4, mm = lane & 15;
    f32x4 acc[4];
#pragma unroll
    for (int nb = 0; nb < 4; ++nb) acc[nb] = (f32x4){0.f, 0.f, 0.f, 0.f};

    const int ar = tid >> 3;                       // 0..31
    const int sslot = (tid & 7) ^ (ar & 7);        // swizzled global k-slot
    const short* Ag = (const short*)A + (size_t)(m0 + ar) * K + sslot * 8;
    const short* Ag2 = (const short*)A + (size_t)(m0 + ar + 32) * K + ((tid & 7) ^ ((ar + 32) & 7)) * 8;
    const short* Bg = (const short*)BT + (size_t)(n0 + ar) * K + sslot * 8;
    const short* Bg2 = (const short*)BT + (size_t)(n0 + ar + 32) * K + ((tid & 7) ^ ((ar + 32) & 7)) * 8;

    const int xm = mm & 7;
    const short* Asf = (const short*)As;
    const short* Bsf = (const short*)Bs;
    const int aoff0 = (w * 16 + mm) * 64 + ((q4 ^ xm)) * 8;
    const int aoff1 = (w * 16 + mm) * 64 + (((4 + q4) ^ xm)) * 8;
    int boff0[4], boff1[4];
#pragma unroll
    for (int nb = 0; nb < 4; ++nb) {
        boff0[nb] = (nb * 16 + mm) * 64 + ((q4 ^ xm)) * 8;
        boff1[nb] = (nb * 16 + mm) * 64 + (((4 + q4) ^ xm)) * 8;
    }

    for (int k0 = 0; k0 < K; k0 += 64) {
        __syncthreads();
        gload16(Ag + k0, &As[ar][(tid & 7) * 8]);
        gload16(Ag2 + k0, &As[ar + 32][(tid & 7) * 8]);
        gload16(Bg + k0, &Bs[ar][(tid & 7) * 8]);
        gload16(Bg2 + k0, &Bs[ar + 32][(tid & 7) * 8]);
        __syncthreads();   // drains vmcnt (compiler emits it before s_barrier)
        short8 af0 = *(const short8*)(Asf + aoff0);
        short8 af1 = *(const short8*)(Asf + aoff1);
#pragma unroll
        for (int nb = 0; nb < 4; ++nb) {
            short8 b0 = *(const short8*)(Bsf + boff0[nb]);
            short8 b1 = *(const short8*)(Bsf + boff1[nb]);
            acc[nb] = __builtin_amdgcn_mfma_f32_16x16x32_bf16(af0, b0, acc[nb], 0, 0, 0);
            acc[nb] = __builtin_amdgcn_mfma_f32_16x16x32_bf16(af1, b1, acc[nb], 0, 0, 0);
        }
    }
#pragma unroll
    for (int nb = 0; nb < 4; ++nb) {
#pragma unroll
        for (int r = 0; r < 4; ++r) {
            int row = m0 + w * 16 + q4 * 4 + r;
            int col = n0 + nb * 16 + mm;
            C[(size_t)row * N + col] = acc[nb][r] + bias[col];
        }
    }
}

// ---- RMSNorm q and k; emit f16 Q (scale 1/8 folded), f16 K (kvh,t,d), fp32 V ----
// (reverted to R4 — validated; no side buffers)
__global__ __launch_bounds__(256) void norm_kernel(
    const float* __restrict__ qbuf, const float* __restrict__ kvbuf,
    const float* __restrict__ qn_w, const float* __restrict__ kn_w,
    _Float16* __restrict__ qh, _Float16* __restrict__ kh, float* __restrict__ vbuf)
{
    const int t = blockIdx.x;
    const int tid = threadIdx.x;
#pragma unroll
    for (int it = 0; it < 6; ++it) {
        int idx = it * 256 + tid;
        int chunk = idx >> 6;        // 0..15 q heads, 16..19 k kvh, 20..23 v kvh
        int d = idx & 63;
        float val;
        if (chunk < 16)      val = qbuf[(size_t)t * DMODEL + chunk * 64 + d];
        else if (chunk < 20) val = kvbuf[(size_t)t * 512 + (chunk - 16) * 64 + d];
        else                 val = kvbuf[(size_t)t * 512 + 256 + (chunk - 20) * 64 + d];
        if (chunk < 20) {
            float ss = val * val;
#pragma unroll
            for (int j = 32; j > 0; j >>= 1) ss += __shfl_xor(ss, j, 64);
            float rs = 1.0f / sqrtf(ss * (1.0f / 64.0f) + 1e-8f);
            if (chunk < 16) {
                qh[(size_t)t * DMODEL + chunk * 64 + d] =
                    (_Float16)(val * rs * qn_w[d] * 0.125f);
            } else {
                kh[((size_t)(chunk - 16) * TSEQ + t) * HDIM + d] =
                    (_Float16)(val * rs * kn_w[d]);
            }
        } else {
            vbuf[((size_t)(chunk - 20) * TSEQ + t) * HDIM + d] = val;
        }
    }
}

// ---- fused MFMA scores + exact top-64 + softmax + V gather ----
// R3 structure + exact distance pruning with IN-KERNEL bounds (no side buffers):
//   sr = q_h . k_h  with |q_h| computed exactly from the f16 row, and
//   |k_h| <= 8*max|kn_w|*1.001 (RMS norm identity + f16 rounding slack).
//   B = |q_h|*8*max|kn_w|*1.001 + 1e-3 >= any sr (Cauchy-Schwarz; 1e-3 covers
//   f32 MFMA accumulation). Skip chunk if B - slope*dmin < th (strict; ties
//   still examined); block-wide early break via __syncthreads_and. Selection
//   otherwise identical to the validated R3/R4 path.
__global__ __launch_bounds__(1024, 4) void attn_kernel(
    const _Float16* __restrict__ qh, const _Float16* __restrict__ kh,
    const float* __restrict__ vbuf, bf16* __restrict__ ybuf,
    const float* __restrict__ kn_w)
{
    __shared__ float Sg[2][4][16][68];   // [buf][chunk-in-group][qrow][key]
    __shared__ float cbS[16][128];       // per-row candidate scores
    __shared__ int   cbI[16][128];       // per-row candidate indices
    const int tid = threadIdx.x;
    const int w = tid >> 6, lane = tid & 63;
    const int mm = lane & 15, q4 = lane >> 4;
    const int gc = w >> 2, st = w & 3;   // producer role: chunk-in-group, key-subtile
    const int h = 15 - (blockIdx.x & 15);            // low-slope (heavy) heads first
    const int t0 = (127 - (blockIdx.x >> 4)) << 4;   // long rows first
    const int kvh = h >> 2;
    const float slope = exp2f(-((float)h) * (8.0f / 15.0f));
    const _Float16* kbase = kh + (size_t)kvh * TSEQ * HDIM;
    const int nch = (t0 + 15) >> 6;
    const int dbase = t0 + w - 63;       // dist of chunk's last key = dbase - jb

    // per-row exact score upper bound B (wave-uniform)
    float qe = (float)qh[(size_t)(t0 + w) * DMODEL + h * HDIM + lane];
    float qs = qe * qe;
#pragma unroll
    for (int j = 32; j > 0; j >>= 1) qs += __shfl_xor(qs, j, 64);
    float kw = fabsf(kn_w[lane]);
#pragma unroll
    for (int j = 32; j > 0; j >>= 1) kw = fmaxf(kw, __shfl_xor(kw, j, 64));
    const float B = sqrtf(qs) * (8.0f * kw * 1.001f) + 1e-3f;

    // Q fragments (f16, 1/8 scale folded). A-frag: row=lane&15, k=(lane>>4)*8..+7
    const _Float16* qp = qh + (size_t)(t0 + mm) * DMODEL + h * HDIM + q4 * 8;
    half8 qf0 = *(const half8*)(qp);        // d 0..31
    half8 qf1 = *(const half8*)(qp + 32);   // d 32..63

    // prologue: produce group base c=nch into buffer 0
    {
        const int cmy = nch - gc;
        if (cmy >= 0) {
            const int jb = cmy << 6;
            const _Float16* kp = kbase + ((size_t)(jb + st * 16 + mm)) * HDIM + q4 * 8;
            half8 b0 = *(const half8*)(kp);
            half8 b1 = *(const half8*)(kp + 32);
            f32x4 a = __builtin_amdgcn_mfma_f32_16x16x32_f16(
                qf0, b0, (f32x4){0.f, 0.f, 0.f, 0.f}, 0, 0, 0);
            a = __builtin_amdgcn_mfma_f32_16x16x32_f16(qf1, b1, a, 0, 0, 0);
            // C layout: col=lane&15 (key), row=(lane>>4)*4+reg (query)
#pragma unroll
            for (int rr = 0; rr < 4; ++rr)
                Sg[0][gc][q4 * 4 + rr][st * 16 + mm] = a[rr];
        }
    }
    __syncthreads();

    float cs = -1e30f; int ci = 0;   // kept-64 for this wave's row (ascending)
    float th = -1e30f;               // 64th-largest so far (stale ok: weaker gate)
    int cnt0 = 0;                    // pending candidates in buffer
    int p = 0;
    for (int c = nch; c >= 0; c -= 4) {
        // issue next group's K loads early (hide L2 latency under merge)
        const int cmy2 = c - 4 - gc;
        half8 b0, b1;
        if (cmy2 >= 0) {
            const int jb2 = cmy2 << 6;
            const _Float16* kp = kbase + ((size_t)(jb2 + st * 16 + mm)) * HDIM + q4 * 8;
            b0 = *(const half8*)(kp);
            b1 = *(const half8*)(kp + 32);
        }
        // merge up to 4 chunks of current group from Sg[p]; wave w = row t0+w
        for (int gi = 0; gi < 4; ++gi) {
            const int cc = c - gi;
            if (cc < 0) break;
            const int jb = cc << 6;
            // exact prune: no score in chunk can reach th
            int dm = dbase - jb;
            float dmin = (float)(dm > 0 ? dm : 0);
            if (B - slope * dmin < th) continue;
            float sr = Sg[p][gi][w][lane];
            int dist = (t0 + w) - (jb + lane);
            float s = sr - slope * (float)dist;
            bool pass = (dist >= 0) && (s >= th);
            unsigned long long mk = __ballot(pass);
            if (mk) {
                int rank = __popcll(mk & ((1ull << lane) - 1ull));
                if (pass) { cbS[w][cnt0 + rank] = s; cbI[w][cnt0 + rank] = jb + lane; }
                cnt0 += __popcll(mk);
                if (cnt0 >= 64) {
                    float ns = cbS[w][lane];
                    int   ni = cbI[w][lane];
                    bsort(ns, ni, lane);
                    float rsv = __shfl_xor(ns, 63, 64);   // descending view
                    int   riv = __shfl_xor(ni, 63, 64);
                    if (pgt(rsv, riv, cs, ci)) { cs = rsv; ci = riv; }
                    bmerge(cs, ci, lane);                  // restore ascending
                    th = __shfl(cs, 0, 64);
                    int rem = cnt0 - 64;
                    float ms = 0.f; int mi = 0;
                    if (lane < rem) { ms = cbS[w][64 + lane]; mi = cbI[w][64 + lane]; }
                    if (lane < rem) { cbS[w][lane] = ms; cbI[w][lane] = mi; }
                    cnt0 = rem;
                }
            }
        }
        // can ALL remaining chunks (<= c-4) be skipped for my row?
        int dmN = dbase - ((c - 4) << 6);
        float dminN = (float)(dmN > 0 ? dmN : 0);
        int done = (B - slope * dminN < th) ? 1 : 0;
        // produce next group into the other buffer
        if (cmy2 >= 0) {
            f32x4 a = __builtin_amdgcn_mfma_f32_16x16x32_f16(
                qf0, b0, (f32x4){0.f, 0.f, 0.f, 0.f}, 0, 0, 0);
            a = __builtin_amdgcn_mfma_f32_16x16x32_f16(qf1, b1, a, 0, 0, 0);
#pragma unroll
            for (int rr = 0; rr < 4; ++rr)
                Sg[p ^ 1][gc][q4 * 4 + rr][st * 16 + mm] = a[rr];
        }
        p ^= 1;
        if (__syncthreads_and(done)) break;   // exact block-wide early exit
    }
    // flush remaining candidates (pads lose to everything incl. -1e30 kept pads)
    if (cnt0 > 0) {
        float ns = (lane < cnt0) ? cbS[w][lane] : -2e30f;
        int   ni = (lane < cnt0) ? cbI[w][lane] : 0;
        bsort(ns, ni, lane);
        float rsv = __shfl_xor(ns, 63, 64);
        int   riv = __shfl_xor(ni, 63, 64);
        if (pgt(rsv, riv, cs, ci)) { cs = rsv; ci = riv; }
        bmerge(cs, ci, lane);
    }

    // softmax over kept 64 (pads -1e30 -> weight 0); max at lane 63
    float msx = __shfl(cs, 63, 64);
    bool valid = cs > -1e29f;
    float pr = valid ? __expf(cs - msx) : 0.f;
    float l = pr;
#pragma unroll
    for (int j2 = 32; j2 > 0; j2 >>= 1) l += __shfl_xor(l, j2, 64);
    float wgt = pr / l;
    int widx = valid ? ci : 0;
    // V gather via wave broadcast (coalesced: fixed i -> consecutive lanes)
    float acc = 0.f;
    const float* vb = vbuf + (size_t)kvh * TSEQ * HDIM + lane;
#pragma unroll 8
    for (int i = 0; i < 64; ++i) {
        float wv = __shfl(wgt, i, 64);
        int  ix = __shfl(widx, i, 64);
        acc += wv * vb[(size_t)ix * HDIM];
    }
    ybuf[(size_t)(t0 + w) * DMODEL + h * HDIM + lane] = __float2bfloat16(acc);
}

extern "C" void kernel_launch(void* const* d_in, const int* in_sizes, int n_in,
                              void* d_out, int out_size, void* d_ws, size_t ws_size,
                              hipStream_t stream)
{
    // d_in order: x, wq, bq, wkv, bkv, wo, bo, qn_w, kn_w  (all fp32)
    const float* x    = (const float*)d_in[0];
    const float* wq   = (const float*)d_in[1];
    const float* bq   = (const float*)d_in[2];
    const float* wkv  = (const float*)d_in[3];
    const float* bkv  = (const float*)d_in[4];
    const float* wo   = (const float*)d_in[5];
    const float* bo   = (const float*)d_in[6];
    const float* qn_w = (const float*)d_in[7];
    const float* kn_w = (const float*)d_in[8];
    char* ws = (char*)d_ws;
    // ws layout (28 MB):
    // cx bf16 4M @0 (reused as qh f16 4M after kv-gemm) | cwqT 2M @4M | cwkvT 1M @6M |
    // cwoT 2M @7M | qbuf fp32 8M @9M | kvbuf fp32 4M @17M | kh f16 1M @21M |
    // vbuf fp32 2M @22M | ybuf bf16 4M @24M..28M (no other buffer may overlap!)
    bf16*      cx    = (bf16*)(ws);
    bf16*      cwqT  = (bf16*)(ws + ((size_t)4  << 20));   // [1024][1024] (n,k)
    bf16*      cwkvT = (bf16*)(ws + ((size_t)6  << 20));   // [512][1024]  (n,k)
    bf16*      cwoT  = (bf16*)(ws + ((size_t)7  << 20));   // [1024][1024] (n,k)
    float*     qbuf  = (float*)(ws + ((size_t)9  << 20));
    float*     kvbuf = (float*)(ws + ((size_t)17 << 20));
    _Float16*  qh    = (_Float16*)(ws);                      // overlays dead cx
    _Float16*  kh    = (_Float16*)(ws + ((size_t)21 << 20));
    float*     vbuf  = (float*)(ws + ((size_t)22 << 20));
    bf16*      ybuf  = (bf16*)(ws + ((size_t)24 << 20));
    float*     out   = (float*)d_out;   // fp32 output

    convert_x<<<1024, 256, 0, stream>>>(x, cx);
    transpose_conv<<<dim3(32, 32), 256, 0, stream>>>(wq, cwqT, 1024, 1024);
    transpose_conv<<<dim3(16, 32), 256, 0, stream>>>(wkv, cwkvT, 1024, 512);
    transpose_conv<<<dim3(32, 32), 256, 0, stream>>>(wo, cwoT, 1024, 1024);
    gemm_bias<<<dim3(DMODEL / 64, TSEQ / 64), 256, 0, stream>>>(
        cx, cwqT, bq, qbuf, TSEQ, DMODEL, DMODEL);
    gemm_bias<<<dim3(512 / 64, TSEQ / 64), 256, 0, stream>>>(
        cx, cwkvT, bkv, kvbuf, TSEQ, 512, DMODEL);
    norm_kernel<<<TSEQ, 256, 0, stream>>>(qbuf, kvbuf, qn_w, kn_w, qh, kh, vbuf);
    attn_kernel<<<NH * (TSEQ / 16), 1024, 0, stream>>>(qh, kh, vbuf, ybuf, kn_w);
    gemm_bias<<<dim3(DMODEL / 64, TSEQ / 64), 256, 0, stream>>>(
        ybuf, cwoT, bo, out, TSEQ, DMODEL, DMODEL);
}

// Round 8
// 274.647 us; speedup vs baseline: 1.1707x; 1.1707x over previous
//
#include <hip/hip_runtime.h>
#include <hip/hip_bf16.h>
#include <stdint.h>

// Problem constants (fixed by reference)
#define TSEQ   2048
#define DMODEL 1024
#define NH     16
#define HDIM   64
#define NKVH   4

typedef __attribute__((ext_vector_type(8))) short short8;
typedef __attribute__((ext_vector_type(8))) _Float16 half8;
typedef __attribute__((ext_vector_type(4))) float f32x4;
typedef __hip_bfloat16 bf16;

// async global->LDS, 16B per lane (linear LDS dest = wave base + lane*16)
__device__ __forceinline__ void gload16(const void* g, void* l) {
    __builtin_amdgcn_global_load_lds(
        (const __attribute__((address_space(1))) uint32_t*)g,
        (__attribute__((address_space(3))) uint32_t*)l, 16, 0, 0);
}

// priority comparator: higher score wins; tie -> lower index wins (matches jax top_k)
__device__ __forceinline__ bool pgt(float as, int ai, float bs, int bi) {
    return (as > bs) || (as == bs && ai < bi);
}

// full bitonic sort across 64 lanes, ascending by priority (validated R6)
__device__ __forceinline__ void bsort(float& s, int& i, int lane) {
#pragma unroll
    for (int k = 2; k <= 64; k <<= 1) {
#pragma unroll
        for (int j = k >> 1; j > 0; j >>= 1) {
            float os = __shfl_xor(s, j, 64);
            int   oi = __shfl_xor(i, j, 64);
            bool lower = (lane & j) == 0;
            bool asc   = (lane & k) == 0;
            bool wmin  = (lower == asc);
            bool takeo = (pgt(s, i, os, oi) == wmin);
            if (takeo) { s = os; i = oi; }
        }
    }
}

// bitonic -> ascending cleanup (6 stages) (validated R6)
__device__ __forceinline__ void bmerge(float& s, int& i, int lane) {
#pragma unroll
    for (int j = 32; j > 0; j >>= 1) {
        float os = __shfl_xor(s, j, 64);
        int   oi = __shfl_xor(i, j, 64);
        bool lower = (lane & j) == 0;
        bool takeo = (pgt(s, i, os, oi) == lower);
        if (takeo) { s = os; i = oi; }
    }
}

// ---- fp32 -> bf16 conversion of x ----
__global__ __launch_bounds__(256) void convert_x(
    const float* __restrict__ x, bf16* __restrict__ cx)
{
    const size_t i0 = (size_t)blockIdx.x * 256 + threadIdx.x;
    const size_t stride = (size_t)gridDim.x * 256;
    for (size_t i = i0; i < 2097152; i += stride) cx[i] = __float2bfloat16(x[i]);
}

// ---- fp32 [R][C] -> bf16 [C][R] tiled transpose-convert (weights, one-shot) ----
__global__ __launch_bounds__(256) void transpose_conv(
    const float* __restrict__ in, bf16* __restrict__ out, int R, int Cc)
{
    __shared__ float tile[32][33];
    const int bx = blockIdx.x * 32;   // col base (n)
    const int by = blockIdx.y * 32;   // row base (k)
    const int tx = threadIdx.x & 31, ty = threadIdx.x >> 5;   // 32 x 8
#pragma unroll
    for (int i = 0; i < 32; i += 8)
        tile[ty + i][tx] = in[(size_t)(by + ty + i) * Cc + bx + tx];
    __syncthreads();
#pragma unroll
    for (int i = 0; i < 32; i += 8)
        out[(size_t)(bx + ty + i) * R + by + tx] = __float2bfloat16(tile[tx][ty + i]);
}

// ---- MFMA GEMM: C[M,N] fp32 = A[M,K](bf16) @ BT[N,K](bf16)^T + bias[N](fp32)
// (unchanged from R4 — validated)
__global__ __launch_bounds__(256) void gemm_bias(
    const bf16* __restrict__ A, const bf16* __restrict__ BT,
    const float* __restrict__ bias, float* __restrict__ C,
    int M, int N, int K)
{
    __shared__ short As[64][64];   // (m, k-slot-swizzled)  8KB
    __shared__ short Bs[64][64];   // (n, k-slot-swizzled)  8KB
    const int tid = threadIdx.x;
    const int m0 = blockIdx.y * 64, n0 = blockIdx.x * 64;
    const int w = tid >> 6, lane = tid & 63;
    const int q4 = lane >> 4, mm = lane & 15;
    f32x4 acc[4];
#pragma unroll
    for (int nb = 0; nb < 4; ++nb) acc[nb] = (f32x4){0.f, 0.f, 0.f, 0.f};

    const int ar = tid >> 3;                       // 0..31
    const int sslot = (tid & 7) ^ (ar & 7);        // swizzled global k-slot
    const short* Ag = (const short*)A + (size_t)(m0 + ar) * K + sslot * 8;
    const short* Ag2 = (const short*)A + (size_t)(m0 + ar + 32) * K + ((tid & 7) ^ ((ar + 32) & 7)) * 8;
    const short* Bg = (const short*)BT + (size_t)(n0 + ar) * K + sslot * 8;
    const short* Bg2 = (const short*)BT + (size_t)(n0 + ar + 32) * K + ((tid & 7) ^ ((ar + 32) & 7)) * 8;

    const int xm = mm & 7;
    const short* Asf = (const short*)As;
    const short* Bsf = (const short*)Bs;
    const int aoff0 = (w * 16 + mm) * 64 + ((q4 ^ xm)) * 8;
    const int aoff1 = (w * 16 + mm) * 64 + (((4 + q4) ^ xm)) * 8;
    int boff0[4], boff1[4];
#pragma unroll
    for (int nb = 0; nb < 4; ++nb) {
        boff0[nb] = (nb * 16 + mm) * 64 + ((q4 ^ xm)) * 8;
        boff1[nb] = (nb * 16 + mm) * 64 + (((4 + q4) ^ xm)) * 8;
    }

    for (int k0 = 0; k0 < K; k0 += 64) {
        __syncthreads();
        gload16(Ag + k0, &As[ar][(tid & 7) * 8]);
        gload16(Ag2 + k0, &As[ar + 32][(tid & 7) * 8]);
        gload16(Bg + k0, &Bs[ar][(tid & 7) * 8]);
        gload16(Bg2 + k0, &Bs[ar + 32][(tid & 7) * 8]);
        __syncthreads();   // drains vmcnt (compiler emits it before s_barrier)
        short8 af0 = *(const short8*)(Asf + aoff0);
        short8 af1 = *(const short8*)(Asf + aoff1);
#pragma unroll
        for (int nb = 0; nb < 4; ++nb) {
            short8 b0 = *(const short8*)(Bsf + boff0[nb]);
            short8 b1 = *(const short8*)(Bsf + boff1[nb]);
            acc[nb] = __builtin_amdgcn_mfma_f32_16x16x32_bf16(af0, b0, acc[nb], 0, 0, 0);
            acc[nb] = __builtin_amdgcn_mfma_f32_16x16x32_bf16(af1, b1, acc[nb], 0, 0, 0);
        }
    }
#pragma unroll
    for (int nb = 0; nb < 4; ++nb) {
#pragma unroll
        for (int r = 0; r < 4; ++r) {
            int row = m0 + w * 16 + q4 * 4 + r;
            int col = n0 + nb * 16 + mm;
            C[(size_t)row * N + col] = acc[nb][r] + bias[col];
        }
    }
}

// ---- RMSNorm q and k; emit f16 Q (scale 1/8 folded), f16 K (kvh,t,d), fp32 V ----
__global__ __launch_bounds__(256) void norm_kernel(
    const float* __restrict__ qbuf, const float* __restrict__ kvbuf,
    const float* __restrict__ qn_w, const float* __restrict__ kn_w,
    _Float16* __restrict__ qh, _Float16* __restrict__ kh, float* __restrict__ vbuf)
{
    const int t = blockIdx.x;
    const int tid = threadIdx.x;
#pragma unroll
    for (int it = 0; it < 6; ++it) {
        int idx = it * 256 + tid;
        int chunk = idx >> 6;        // 0..15 q heads, 16..19 k kvh, 20..23 v kvh
        int d = idx & 63;
        float val;
        if (chunk < 16)      val = qbuf[(size_t)t * DMODEL + chunk * 64 + d];
        else if (chunk < 20) val = kvbuf[(size_t)t * 512 + (chunk - 16) * 64 + d];
        else                 val = kvbuf[(size_t)t * 512 + 256 + (chunk - 20) * 64 + d];
        if (chunk < 20) {
            float ss = val * val;
#pragma unroll
            for (int j = 32; j > 0; j >>= 1) ss += __shfl_xor(ss, j, 64);
            float rs = 1.0f / sqrtf(ss * (1.0f / 64.0f) + 1e-8f);
            if (chunk < 16) {
                qh[(size_t)t * DMODEL + chunk * 64 + d] =
                    (_Float16)(val * rs * qn_w[d] * 0.125f);
            } else {
                kh[((size_t)(chunk - 16) * TSEQ + t) * HDIM + d] =
                    (_Float16)(val * rs * kn_w[d]);
            }
        } else {
            vbuf[((size_t)(chunk - 20) * TSEQ + t) * HDIM + d] = val;
        }
    }
}

// ---- fused MFMA scores + exact top-64 + softmax + V gather ----
// R4 structure (plain __syncthreads, validated) + STATIC per-block window:
//   For any row with >=64 causal keys, th >= L = -B - 63*slope (each of the
//   nearest 64 keys has s >= -|q||k| - slope*63 >= L). A key at distance
//   d > 2B/slope + 63 has s <= B - slope*d < L <= th_true -> strictly below
//   the 64th value -> exactly prunable (ties unaffected). c_min computed once
//   per block (one extra barrier); production, loads and merges all stop at
//   c_min. No per-iteration sync overhead (R7's __syncthreads_and removed).
//   Per-wave runtime continue-gate retained (validated R7).
__global__ __launch_bounds__(1024, 4) void attn_kernel(
    const _Float16* __restrict__ qh, const _Float16* __restrict__ kh,
    const float* __restrict__ vbuf, bf16* __restrict__ ybuf,
    const float* __restrict__ kn_w)
{
    __shared__ float Sg[2][4][16][68];   // [buf][chunk-in-group][qrow][key]
    __shared__ float cbS[16][128];       // per-row candidate scores
    __shared__ int   cbI[16][128];       // per-row candidate indices
    __shared__ int   emin[16];           // per-wave earliest needed key
    const int tid = threadIdx.x;
    const int w = tid >> 6, lane = tid & 63;
    const int mm = lane & 15, q4 = lane >> 4;
    const int gc = w >> 2, st = w & 3;   // producer role: chunk-in-group, key-subtile
    const int h = 15 - (blockIdx.x >> 7);            // heavy (low-slope) heads first
    const int t0 = (127 - (blockIdx.x & 127)) << 4;  // long rows first within head
    const int kvh = h >> 2;
    const float slope = exp2f(-((float)h) * (8.0f / 15.0f));
    const _Float16* kbase = kh + (size_t)kvh * TSEQ * HDIM;
    const int nch = (t0 + 15) >> 6;
    const int dbase = t0 + w - 63;       // dist of chunk's last key = dbase - jb

    // per-row exact score upper bound B (wave-uniform); window D = 2B/slope+64
    float qe = (float)qh[(size_t)(t0 + w) * DMODEL + h * HDIM + lane];
    float qs = qe * qe;
#pragma unroll
    for (int j = 32; j > 0; j >>= 1) qs += __shfl_xor(qs, j, 64);
    float kw = fabsf(kn_w[lane]);
#pragma unroll
    for (int j = 32; j > 0; j >>= 1) kw = fmaxf(kw, __shfl_xor(kw, j, 64));
    const float B = sqrtf(qs) * (8.0f * kw * 1.001f) + 1e-3f;
    if (lane == 0) {
        float Dw = 2.0f * B / slope + 64.0f;
        emin[w] = (int)floorf((float)(t0 + w) - Dw);
    }

    // Q fragments (f16, 1/8 scale folded). A-frag: row=lane&15, k=(lane>>4)*8..+7
    const _Float16* qp = qh + (size_t)(t0 + mm) * DMODEL + h * HDIM + q4 * 8;
    half8 qf0 = *(const half8*)(qp);        // d 0..31
    half8 qf1 = *(const half8*)(qp + 32);   // d 32..63

    // prologue: produce group base c=nch into buffer 0 (newest chunks always needed)
    {
        const int cmy = nch - gc;
        if (cmy >= 0) {
            const int jb = cmy << 6;
            const _Float16* kp = kbase + ((size_t)(jb + st * 16 + mm)) * HDIM + q4 * 8;
            half8 b0 = *(const half8*)(kp);
            half8 b1 = *(const half8*)(kp + 32);
            f32x4 a = __builtin_amdgcn_mfma_f32_16x16x32_f16(
                qf0, b0, (f32x4){0.f, 0.f, 0.f, 0.f}, 0, 0, 0);
            a = __builtin_amdgcn_mfma_f32_16x16x32_f16(qf1, b1, a, 0, 0, 0);
            // C layout: col=lane&15 (key), row=(lane>>4)*4+reg (query)
#pragma unroll
            for (int rr = 0; rr < 4; ++rr)
                Sg[0][gc][q4 * 4 + rr][st * 16 + mm] = a[rr];
        }
    }
    __syncthreads();

    // block-uniform earliest chunk (conservative: min over rows)
    int em = emin[0];
#pragma unroll
    for (int i = 1; i < 16; ++i) em = min(em, emin[i]);
    const int c_min = (em > 0) ? (em >> 6) : 0;

    float cs = -1e30f; int ci = 0;   // kept-64 for this wave's row (ascending)
    float th = -1e30f;               // 64th-largest so far (stale ok: weaker gate)
    int cnt0 = 0;                    // pending candidates in buffer
    int p = 0;
    for (int c = nch; c >= c_min; c -= 4) {
        // issue next group's K loads early (hide L2 latency under merge)
        const int cmy2 = c - 4 - gc;
        half8 b0, b1;
        if (cmy2 >= c_min) {
            const int jb2 = cmy2 << 6;
            const _Float16* kp = kbase + ((size_t)(jb2 + st * 16 + mm)) * HDIM + q4 * 8;
            b0 = *(const half8*)(kp);
            b1 = *(const half8*)(kp + 32);
        }
        // merge up to 4 chunks of current group from Sg[p]; wave w = row t0+w
        for (int gi = 0; gi < 4; ++gi) {
            const int cc = c - gi;
            if (cc < c_min) break;
            const int jb = cc << 6;
            // per-wave runtime prune (validated R7): chunk can't reach th
            int dm = dbase - jb;
            float dmin = (float)(dm > 0 ? dm : 0);
            if (B - slope * dmin < th) continue;
            float sr = Sg[p][gi][w][lane];
            int dist = (t0 + w) - (jb + lane);
            float s = sr - slope * (float)dist;
            bool pass = (dist >= 0) && (s >= th);
            unsigned long long mk = __ballot(pass);
            if (mk) {
                int rank = __popcll(mk & ((1ull << lane) - 1ull));
                if (pass) { cbS[w][cnt0 + rank] = s; cbI[w][cnt0 + rank] = jb + lane; }
                cnt0 += __popcll(mk);
                if (cnt0 >= 64) {
                    float ns = cbS[w][lane];
                    int   ni = cbI[w][lane];
                    bsort(ns, ni, lane);
                    float rsv = __shfl_xor(ns, 63, 64);   // descending view
                    int   riv = __shfl_xor(ni, 63, 64);
                    if (pgt(rsv, riv, cs, ci)) { cs = rsv; ci = riv; }
                    bmerge(cs, ci, lane);                  // restore ascending
                    th = __shfl(cs, 0, 64);
                    int rem = cnt0 - 64;
                    float ms = 0.f; int mi = 0;
                    if (lane < rem) { ms = cbS[w][64 + lane]; mi = cbI[w][64 + lane]; }
                    if (lane < rem) { cbS[w][lane] = ms; cbI[w][lane] = mi; }
                    cnt0 = rem;
                }
            }
        }
        // produce next group into the other buffer
        if (cmy2 >= c_min) {
            f32x4 a = __builtin_amdgcn_mfma_f32_16x16x32_f16(
                qf0, b0, (f32x4){0.f, 0.f, 0.f, 0.f}, 0, 0, 0);
            a = __builtin_amdgcn_mfma_f32_16x16x32_f16(qf1, b1, a, 0, 0, 0);
#pragma unroll
            for (int rr = 0; rr < 4; ++rr)
                Sg[p ^ 1][gc][q4 * 4 + rr][st * 16 + mm] = a[rr];
        }
        p ^= 1;
        __syncthreads();
    }
    // flush remaining candidates (pads lose to everything incl. -1e30 kept pads)
    if (cnt0 > 0) {
        float ns = (lane < cnt0) ? cbS[w][lane] : -2e30f;
        int   ni = (lane < cnt0) ? cbI[w][lane] : 0;
        bsort(ns, ni, lane);
        float rsv = __shfl_xor(ns, 63, 64);
        int   riv = __shfl_xor(ni, 63, 64);
        if (pgt(rsv, riv, cs, ci)) { cs = rsv; ci = riv; }
        bmerge(cs, ci, lane);
    }

    // softmax over kept 64 (pads -1e30 -> weight 0); max at lane 63
    float msx = __shfl(cs, 63, 64);
    bool valid = cs > -1e29f;
    float pr = valid ? __expf(cs - msx) : 0.f;
    float l = pr;
#pragma unroll
    for (int j2 = 32; j2 > 0; j2 >>= 1) l += __shfl_xor(l, j2, 64);
    float wgt = pr / l;
    int widx = valid ? ci : 0;
    // V gather via wave broadcast (coalesced: fixed i -> consecutive lanes)
    float acc = 0.f;
    const float* vb = vbuf + (size_t)kvh * TSEQ * HDIM + lane;
#pragma unroll 8
    for (int i = 0; i < 64; ++i) {
        float wv = __shfl(wgt, i, 64);
        int  ix = __shfl(widx, i, 64);
        acc += wv * vb[(size_t)ix * HDIM];
    }
    ybuf[(size_t)(t0 + w) * DMODEL + h * HDIM + lane] = __float2bfloat16(acc);
}

extern "C" void kernel_launch(void* const* d_in, const int* in_sizes, int n_in,
                              void* d_out, int out_size, void* d_ws, size_t ws_size,
                              hipStream_t stream)
{
    // d_in order: x, wq, bq, wkv, bkv, wo, bo, qn_w, kn_w  (all fp32)
    const float* x    = (const float*)d_in[0];
    const float* wq   = (const float*)d_in[1];
    const float* bq   = (const float*)d_in[2];
    const float* wkv  = (const float*)d_in[3];
    const float* bkv  = (const float*)d_in[4];
    const float* wo   = (const float*)d_in[5];
    const float* bo   = (const float*)d_in[6];
    const float* qn_w = (const float*)d_in[7];
    const float* kn_w = (const float*)d_in[8];
    char* ws = (char*)d_ws;
    // ws layout (28 MB):
    // cx bf16 4M @0 (reused as qh f16 4M after kv-gemm) | cwqT 2M @4M | cwkvT 1M @6M |
    // cwoT 2M @7M | qbuf fp32 8M @9M | kvbuf fp32 4M @17M | kh f16 1M @21M |
    // vbuf fp32 2M @22M | ybuf bf16 4M @24M..28M (no other buffer may overlap!)
    bf16*      cx    = (bf16*)(ws);
    bf16*      cwqT  = (bf16*)(ws + ((size_t)4  << 20));   // [1024][1024] (n,k)
    bf16*      cwkvT = (bf16*)(ws + ((size_t)6  << 20));   // [512][1024]  (n,k)
    bf16*      cwoT  = (bf16*)(ws + ((size_t)7  << 20));   // [1024][1024] (n,k)
    float*     qbuf  = (float*)(ws + ((size_t)9  << 20));
    float*     kvbuf = (float*)(ws + ((size_t)17 << 20));
    _Float16*  qh    = (_Float16*)(ws);                      // overlays dead cx
    _Float16*  kh    = (_Float16*)(ws + ((size_t)21 << 20));
    float*     vbuf  = (float*)(ws + ((size_t)22 << 20));
    bf16*      ybuf  = (bf16*)(ws + ((size_t)24 << 20));
    float*     out   = (float*)d_out;   // fp32 output

    convert_x<<<1024, 256, 0, stream>>>(x, cx);
    transpose_conv<<<dim3(32, 32), 256, 0, stream>>>(wq, cwqT, 1024, 1024);
    transpose_conv<<<dim3(16, 32), 256, 0, stream>>>(wkv, cwkvT, 1024, 512);
    transpose_conv<<<dim3(32, 32), 256, 0, stream>>>(wo, cwoT, 1024, 1024);
    gemm_bias<<<dim3(DMODEL / 64, TSEQ / 64), 256, 0, stream>>>(
        cx, cwqT, bq, qbuf, TSEQ, DMODEL, DMODEL);
    gemm_bias<<<dim3(512 / 64, TSEQ / 64), 256, 0, stream>>>(
        cx, cwkvT, bkv, kvbuf, TSEQ, 512, DMODEL);
    norm_kernel<<<TSEQ, 256, 0, stream>>>(qbuf, kvbuf, qn_w, kn_w, qh, kh, vbuf);
    attn_kernel<<<NH * (TSEQ / 16), 1024, 0, stream>>>(qh, kh, vbuf, ybuf, kn_w);
    gemm_bias<<<dim3(DMODEL / 64, TSEQ / 64), 256, 0, stream>>>(
        ybuf, cwoT, bo, out, TSEQ, DMODEL, DMODEL);
}

// Round 9
// 262.417 us; speedup vs baseline: 1.2252x; 1.0466x over previous
//
#include <hip/hip_runtime.h>
#include <hip/hip_bf16.h>
#include <stdint.h>

// Problem constants (fixed by reference)
#define TSEQ   2048
#define DMODEL 1024
#define NH     16
#define HDIM   64
#define NKVH   4

typedef __attribute__((ext_vector_type(8))) short short8;
typedef __attribute__((ext_vector_type(8))) _Float16 half8;
typedef __attribute__((ext_vector_type(4))) float f32x4;
typedef __hip_bfloat16 bf16;

// async global->LDS, 16B per lane (linear LDS dest = wave base + lane*16)
__device__ __forceinline__ void gload16(const void* g, void* l) {
    __builtin_amdgcn_global_load_lds(
        (const __attribute__((address_space(1))) uint32_t*)g,
        (__attribute__((address_space(3))) uint32_t*)l, 16, 0, 0);
}

// priority comparator: higher score wins; tie -> lower index wins (matches jax top_k)
__device__ __forceinline__ bool pgt(float as, int ai, float bs, int bi) {
    return (as > bs) || (as == bs && ai < bi);
}

// full bitonic sort across 64 lanes, ascending by priority (validated R6)
__device__ __forceinline__ void bsort(float& s, int& i, int lane) {
#pragma unroll
    for (int k = 2; k <= 64; k <<= 1) {
#pragma unroll
        for (int j = k >> 1; j > 0; j >>= 1) {
            float os = __shfl_xor(s, j, 64);
            int   oi = __shfl_xor(i, j, 64);
            bool lower = (lane & j) == 0;
            bool asc   = (lane & k) == 0;
            bool wmin  = (lower == asc);
            bool takeo = (pgt(s, i, os, oi) == wmin);
            if (takeo) { s = os; i = oi; }
        }
    }
}

// bitonic -> ascending cleanup (6 stages) (validated R6)
__device__ __forceinline__ void bmerge(float& s, int& i, int lane) {
#pragma unroll
    for (int j = 32; j > 0; j >>= 1) {
        float os = __shfl_xor(s, j, 64);
        int   oi = __shfl_xor(i, j, 64);
        bool lower = (lane & j) == 0;
        bool takeo = (pgt(s, i, os, oi) == lower);
        if (takeo) { s = os; i = oi; }
    }
}

// ---- fp32 -> bf16 conversion of x ----
__global__ __launch_bounds__(256) void convert_x(
    const float* __restrict__ x, bf16* __restrict__ cx)
{
    const size_t i0 = (size_t)blockIdx.x * 256 + threadIdx.x;
    const size_t stride = (size_t)gridDim.x * 256;
    for (size_t i = i0; i < 2097152; i += stride) cx[i] = __float2bfloat16(x[i]);
}

// ---- fp32 [R][C] -> bf16 [C][R] tiled transpose-convert (weights, one-shot) ----
__global__ __launch_bounds__(256) void transpose_conv(
    const float* __restrict__ in, bf16* __restrict__ out, int R, int Cc)
{
    __shared__ float tile[32][33];
    const int bx = blockIdx.x * 32;   // col base (n)
    const int by = blockIdx.y * 32;   // row base (k)
    const int tx = threadIdx.x & 31, ty = threadIdx.x >> 5;   // 32 x 8
#pragma unroll
    for (int i = 0; i < 32; i += 8)
        tile[ty + i][tx] = in[(size_t)(by + ty + i) * Cc + bx + tx];
    __syncthreads();
#pragma unroll
    for (int i = 0; i < 32; i += 8)
        out[(size_t)(bx + ty + i) * R + by + tx] = __float2bfloat16(tile[tx][ty + i]);
}

// ---- MFMA GEMM: C[M,N] fp32 = A[M,K](bf16) @ BT[N,K](bf16)^T + bias[N](fp32)
// (unchanged from R4 — validated)
__global__ __launch_bounds__(256) void gemm_bias(
    const bf16* __restrict__ A, const bf16* __restrict__ BT,
    const float* __restrict__ bias, float* __restrict__ C,
    int M, int N, int K)
{
    __shared__ short As[64][64];   // (m, k-slot-swizzled)  8KB
    __shared__ short Bs[64][64];   // (n, k-slot-swizzled)  8KB
    const int tid = threadIdx.x;
    const int m0 = blockIdx.y * 64, n0 = blockIdx.x * 64;
    const int w = tid >> 6, lane = tid & 63;
    const int q4 = lane >> 4, mm = lane & 15;
    f32x4 acc[4];
#pragma unroll
    for (int nb = 0; nb < 4; ++nb) acc[nb] = (f32x4){0.f, 0.f, 0.f, 0.f};

    const int ar = tid >> 3;                       // 0..31
    const int sslot = (tid & 7) ^ (ar & 7);        // swizzled global k-slot
    const short* Ag = (const short*)A + (size_t)(m0 + ar) * K + sslot * 8;
    const short* Ag2 = (const short*)A + (size_t)(m0 + ar + 32) * K + ((tid & 7) ^ ((ar + 32) & 7)) * 8;
    const short* Bg = (const short*)BT + (size_t)(n0 + ar) * K + sslot * 8;
    const short* Bg2 = (const short*)BT + (size_t)(n0 + ar + 32) * K + ((tid & 7) ^ ((ar + 32) & 7)) * 8;

    const int xm = mm & 7;
    const short* Asf = (const short*)As;
    const short* Bsf = (const short*)Bs;
    const int aoff0 = (w * 16 + mm) * 64 + ((q4 ^ xm)) * 8;
    const int aoff1 = (w * 16 + mm) * 64 + (((4 + q4) ^ xm)) * 8;
    int boff0[4], boff1[4];
#pragma unroll
    for (int nb = 0; nb < 4; ++nb) {
        boff0[nb] = (nb * 16 + mm) * 64 + ((q4 ^ xm)) * 8;
        boff1[nb] = (nb * 16 + mm) * 64 + (((4 + q4) ^ xm)) * 8;
    }

    for (int k0 = 0; k0 < K; k0 += 64) {
        __syncthreads();
        gload16(Ag + k0, &As[ar][(tid & 7) * 8]);
        gload16(Ag2 + k0, &As[ar + 32][(tid & 7) * 8]);
        gload16(Bg + k0, &Bs[ar][(tid & 7) * 8]);
        gload16(Bg2 + k0, &Bs[ar + 32][(tid & 7) * 8]);
        __syncthreads();   // drains vmcnt (compiler emits it before s_barrier)
        short8 af0 = *(const short8*)(Asf + aoff0);
        short8 af1 = *(const short8*)(Asf + aoff1);
#pragma unroll
        for (int nb = 0; nb < 4; ++nb) {
            short8 b0 = *(const short8*)(Bsf + boff0[nb]);
            short8 b1 = *(const short8*)(Bsf + boff1[nb]);
            acc[nb] = __builtin_amdgcn_mfma_f32_16x16x32_bf16(af0, b0, acc[nb], 0, 0, 0);
            acc[nb] = __builtin_amdgcn_mfma_f32_16x16x32_bf16(af1, b1, acc[nb], 0, 0, 0);
        }
    }
#pragma unroll
    for (int nb = 0; nb < 4; ++nb) {
#pragma unroll
        for (int r = 0; r < 4; ++r) {
            int row = m0 + w * 16 + q4 * 4 + r;
            int col = n0 + nb * 16 + mm;
            C[(size_t)row * N + col] = acc[nb][r] + bias[col];
        }
    }
}

// ---- RMSNorm q and k; emit f16 Q (scale 1/8 folded), f16 K (kvh,t,d), fp32 V ----
__global__ __launch_bounds__(256) void norm_kernel(
    const float* __restrict__ qbuf, const float* __restrict__ kvbuf,
    const float* __restrict__ qn_w, const float* __restrict__ kn_w,
    _Float16* __restrict__ qh, _Float16* __restrict__ kh, float* __restrict__ vbuf)
{
    const int t = blockIdx.x;
    const int tid = threadIdx.x;
#pragma unroll
    for (int it = 0; it < 6; ++it) {
        int idx = it * 256 + tid;
        int chunk = idx >> 6;        // 0..15 q heads, 16..19 k kvh, 20..23 v kvh
        int d = idx & 63;
        float val;
        if (chunk < 16)      val = qbuf[(size_t)t * DMODEL + chunk * 64 + d];
        else if (chunk < 20) val = kvbuf[(size_t)t * 512 + (chunk - 16) * 64 + d];
        else                 val = kvbuf[(size_t)t * 512 + 256 + (chunk - 20) * 64 + d];
        if (chunk < 20) {
            float ss = val * val;
#pragma unroll
            for (int j = 32; j > 0; j >>= 1) ss += __shfl_xor(ss, j, 64);
            float rs = 1.0f / sqrtf(ss * (1.0f / 64.0f) + 1e-8f);
            if (chunk < 16) {
                qh[(size_t)t * DMODEL + chunk * 64 + d] =
                    (_Float16)(val * rs * qn_w[d] * 0.125f);
            } else {
                kh[((size_t)(chunk - 16) * TSEQ + t) * HDIM + d] =
                    (_Float16)(val * rs * kn_w[d]);
            }
        } else {
            vbuf[((size_t)(chunk - 20) * TSEQ + t) * HDIM + d] = val;
        }
    }
}

// ---- fused MFMA scores + exact top-64 + softmax + V gather ----
// R8 semantics (static window + per-row runtime gate, both validated) with a
// 4-WAVE block: 256 threads, one (h, 16-row) tile. Per round (one 64-key
// chunk): wave w MFMA-produces key-subtile w (4 waves = full chunk) into a
// double-buffered Sg; each wave then merges 4 rows (r = 4w+rr, register
// state, statically indexed). LDS ~25KB -> 6 blocks/CU, 24 waves/CU; barrier
// radius 4 waves. Selection/sort/softmax/gather code identical per row.
__global__ __launch_bounds__(256, 6) void attn_kernel(
    const _Float16* __restrict__ qh, const _Float16* __restrict__ kh,
    const float* __restrict__ vbuf, bf16* __restrict__ ybuf,
    const float* __restrict__ kn_w)
{
    __shared__ float Sg[2][16][68];      // [buf][qrow][key] one chunk
    __shared__ float cbS[16][128];       // per-row candidate scores
    __shared__ int   cbI[16][128];       // per-row candidate indices
    __shared__ int   eminS[4];           // per-wave earliest needed key
    const int tid = threadIdx.x;
    const int w = tid >> 6, lane = tid & 63;
    const int mm = lane & 15, q4 = lane >> 4;
    const int h = 15 - (blockIdx.x >> 7);            // heavy (low-slope) heads first
    const int t0 = (127 - (blockIdx.x & 127)) << 4;  // long rows first within head
    const int kvh = h >> 2;
    const float slope = exp2f(-((float)h) * (8.0f / 15.0f));
    const _Float16* kbase = kh + (size_t)kvh * TSEQ * HDIM;
    const int nch = (t0 + 15) >> 6;

    // max |kn_w| (wave-uniform)
    float kw = fabsf(kn_w[lane]);
#pragma unroll
    for (int j = 32; j > 0; j >>= 1) kw = fmaxf(kw, __shfl_xor(kw, j, 64));
    const float kfac = 8.0f * kw * 1.001f;

    // per-row exact bound B and window for this wave's rows r = 4w+rr
    float Brow[4];
    int em = 0x7fffffff;
#pragma unroll
    for (int rr = 0; rr < 4; ++rr) {
        const int r = 4 * w + rr;
        float qe = (float)qh[(size_t)(t0 + r) * DMODEL + h * HDIM + lane];
        float qs = qe * qe;
#pragma unroll
        for (int j = 32; j > 0; j >>= 1) qs += __shfl_xor(qs, j, 64);
        Brow[rr] = sqrtf(qs) * kfac + 1e-3f;
        float Dw = 2.0f * Brow[rr] / slope + 64.0f;
        int e = (int)floorf((float)(t0 + r) - Dw);
        em = min(em, e);
    }
    if (lane == 0) eminS[w] = em;

    // Q fragments (f16, 1/8 scale folded). A-frag: row=lane&15, k=(lane>>4)*8..+7
    const _Float16* qp = qh + (size_t)(t0 + mm) * DMODEL + h * HDIM + q4 * 8;
    half8 qf0 = *(const half8*)(qp);        // d 0..31
    half8 qf1 = *(const half8*)(qp + 32);   // d 32..63

    // prologue: produce chunk nch into buffer 0 (wave w -> keys w*16..w*16+15)
    {
        const int jb = nch << 6;
        const _Float16* kp = kbase + ((size_t)(jb + w * 16 + mm)) * HDIM + q4 * 8;
        half8 b0 = *(const half8*)(kp);
        half8 b1 = *(const half8*)(kp + 32);
        f32x4 a = __builtin_amdgcn_mfma_f32_16x16x32_f16(
            qf0, b0, (f32x4){0.f, 0.f, 0.f, 0.f}, 0, 0, 0);
        a = __builtin_amdgcn_mfma_f32_16x16x32_f16(qf1, b1, a, 0, 0, 0);
        // C layout: col=lane&15 (key), row=(lane>>4)*4+reg (query)
#pragma unroll
        for (int rr = 0; rr < 4; ++rr)
            Sg[0][q4 * 4 + rr][w * 16 + mm] = a[rr];
    }
    __syncthreads();

    // block-uniform earliest chunk (conservative: min over all rows)
    int em4 = min(min(eminS[0], eminS[1]), min(eminS[2], eminS[3]));
    const int c_min = (em4 > 0) ? (em4 >> 6) : 0;

    float cs[4]; int ci[4]; float thr[4]; int cnt[4];
#pragma unroll
    for (int rr = 0; rr < 4; ++rr) { cs[rr] = -1e30f; ci[rr] = 0; thr[rr] = -1e30f; cnt[rr] = 0; }

    int p = 0;
    for (int c = nch; c >= c_min; --c) {
        // issue next chunk's K loads early (hide L2 latency under merge)
        const int cn = c - 1;
        half8 b0, b1;
        if (cn >= c_min) {
            const _Float16* kp = kbase + ((size_t)((cn << 6) + w * 16 + mm)) * HDIM + q4 * 8;
            b0 = *(const half8*)(kp);
            b1 = *(const half8*)(kp + 32);
        }
        // merge chunk c for this wave's 4 rows
        const int jb = c << 6;
#pragma unroll
        for (int rr = 0; rr < 4; ++rr) {
            const int r = 4 * w + rr;
            // per-row runtime prune (validated): chunk can't reach th
            int dm = (t0 + r - 63) - jb;
            float dmin = (float)(dm > 0 ? dm : 0);
            if (Brow[rr] - slope * dmin < thr[rr]) continue;
            float sr = Sg[p][r][lane];
            int dist = (t0 + r) - (jb + lane);
            float s = sr - slope * (float)dist;
            bool pass = (dist >= 0) && (s >= thr[rr]);
            unsigned long long mk = __ballot(pass);
            if (mk) {
                int rank = __popcll(mk & ((1ull << lane) - 1ull));
                if (pass) { cbS[r][cnt[rr] + rank] = s; cbI[r][cnt[rr] + rank] = jb + lane; }
                cnt[rr] += __popcll(mk);
                if (cnt[rr] >= 64) {
                    float ns = cbS[r][lane];
                    int   ni = cbI[r][lane];
                    bsort(ns, ni, lane);
                    float rsv = __shfl_xor(ns, 63, 64);   // descending view
                    int   riv = __shfl_xor(ni, 63, 64);
                    if (pgt(rsv, riv, cs[rr], ci[rr])) { cs[rr] = rsv; ci[rr] = riv; }
                    bmerge(cs[rr], ci[rr], lane);          // restore ascending
                    thr[rr] = __shfl(cs[rr], 0, 64);
                    int rem = cnt[rr] - 64;
                    float ms = 0.f; int mi = 0;
                    if (lane < rem) { ms = cbS[r][64 + lane]; mi = cbI[r][64 + lane]; }
                    if (lane < rem) { cbS[r][lane] = ms; cbI[r][lane] = mi; }
                    cnt[rr] = rem;
                }
            }
        }
        // produce next chunk into the other buffer
        if (cn >= c_min) {
            f32x4 a = __builtin_amdgcn_mfma_f32_16x16x32_f16(
                qf0, b0, (f32x4){0.f, 0.f, 0.f, 0.f}, 0, 0, 0);
            a = __builtin_amdgcn_mfma_f32_16x16x32_f16(qf1, b1, a, 0, 0, 0);
#pragma unroll
            for (int rr = 0; rr < 4; ++rr)
                Sg[p ^ 1][q4 * 4 + rr][w * 16 + mm] = a[rr];
        }
        p ^= 1;
        __syncthreads();
    }

    // epilogue per row: flush, softmax, V gather, store
    const float* vb = vbuf + (size_t)kvh * TSEQ * HDIM + lane;
#pragma unroll
    for (int rr = 0; rr < 4; ++rr) {
        const int r = 4 * w + rr;
        if (cnt[rr] > 0) {
            float ns = (lane < cnt[rr]) ? cbS[r][lane] : -2e30f;
            int   ni = (lane < cnt[rr]) ? cbI[r][lane] : 0;
            bsort(ns, ni, lane);
            float rsv = __shfl_xor(ns, 63, 64);
            int   riv = __shfl_xor(ni, 63, 64);
            if (pgt(rsv, riv, cs[rr], ci[rr])) { cs[rr] = rsv; ci[rr] = riv; }
            bmerge(cs[rr], ci[rr], lane);
        }
        // softmax over kept 64 (pads -1e30 -> weight 0); max at lane 63
        float msx = __shfl(cs[rr], 63, 64);
        bool valid = cs[rr] > -1e29f;
        float pr = valid ? __expf(cs[rr] - msx) : 0.f;
        float l = pr;
#pragma unroll
        for (int j2 = 32; j2 > 0; j2 >>= 1) l += __shfl_xor(l, j2, 64);
        float wgt = pr / l;
        int widx = valid ? ci[rr] : 0;
        float acc = 0.f;
#pragma unroll 8
        for (int i = 0; i < 64; ++i) {
            float wv = __shfl(wgt, i, 64);
            int  ix = __shfl(widx, i, 64);
            acc += wv * vb[(size_t)ix * HDIM];
        }
        ybuf[(size_t)(t0 + r) * DMODEL + h * HDIM + lane] = __float2bfloat16(acc);
    }
}

extern "C" void kernel_launch(void* const* d_in, const int* in_sizes, int n_in,
                              void* d_out, int out_size, void* d_ws, size_t ws_size,
                              hipStream_t stream)
{
    // d_in order: x, wq, bq, wkv, bkv, wo, bo, qn_w, kn_w  (all fp32)
    const float* x    = (const float*)d_in[0];
    const float* wq   = (const float*)d_in[1];
    const float* bq   = (const float*)d_in[2];
    const float* wkv  = (const float*)d_in[3];
    const float* bkv  = (const float*)d_in[4];
    const float* wo   = (const float*)d_in[5];
    const float* bo   = (const float*)d_in[6];
    const float* qn_w = (const float*)d_in[7];
    const float* kn_w = (const float*)d_in[8];
    char* ws = (char*)d_ws;
    // ws layout (28 MB):
    // cx bf16 4M @0 (reused as qh f16 4M after kv-gemm) | cwqT 2M @4M | cwkvT 1M @6M |
    // cwoT 2M @7M | qbuf fp32 8M @9M | kvbuf fp32 4M @17M | kh f16 1M @21M |
    // vbuf fp32 2M @22M | ybuf bf16 4M @24M..28M (no other buffer may overlap!)
    bf16*      cx    = (bf16*)(ws);
    bf16*      cwqT  = (bf16*)(ws + ((size_t)4  << 20));   // [1024][1024] (n,k)
    bf16*      cwkvT = (bf16*)(ws + ((size_t)6  << 20));   // [512][1024]  (n,k)
    bf16*      cwoT  = (bf16*)(ws + ((size_t)7  << 20));   // [1024][1024] (n,k)
    float*     qbuf  = (float*)(ws + ((size_t)9  << 20));
    float*     kvbuf = (float*)(ws + ((size_t)17 << 20));
    _Float16*  qh    = (_Float16*)(ws);                      // overlays dead cx
    _Float16*  kh    = (_Float16*)(ws + ((size_t)21 << 20));
    float*     vbuf  = (float*)(ws + ((size_t)22 << 20));
    bf16*      ybuf  = (bf16*)(ws + ((size_t)24 << 20));
    float*     out   = (float*)d_out;   // fp32 output

    convert_x<<<1024, 256, 0, stream>>>(x, cx);
    transpose_conv<<<dim3(32, 32), 256, 0, stream>>>(wq, cwqT, 1024, 1024);
    transpose_conv<<<dim3(16, 32), 256, 0, stream>>>(wkv, cwkvT, 1024, 512);
    transpose_conv<<<dim3(32, 32), 256, 0, stream>>>(wo, cwoT, 1024, 1024);
    gemm_bias<<<dim3(DMODEL / 64, TSEQ / 64), 256, 0, stream>>>(
        cx, cwqT, bq, qbuf, TSEQ, DMODEL, DMODEL);
    gemm_bias<<<dim3(512 / 64, TSEQ / 64), 256, 0, stream>>>(
        cx, cwkvT, bkv, kvbuf, TSEQ, 512, DMODEL);
    norm_kernel<<<TSEQ, 256, 0, stream>>>(qbuf, kvbuf, qn_w, kn_w, qh, kh, vbuf);
    attn_kernel<<<NH * (TSEQ / 16), 256, 0, stream>>>(qh, kh, vbuf, ybuf, kn_w);
    gemm_bias<<<dim3(DMODEL / 64, TSEQ / 64), 256, 0, stream>>>(
        ybuf, cwoT, bo, out, TSEQ, DMODEL, DMODEL);
}

// Round 10
// 252.885 us; speedup vs baseline: 1.2714x; 1.0377x over previous
//
#include <hip/hip_runtime.h>
#include <hip/hip_bf16.h>
#include <stdint.h>

// Problem constants (fixed by reference)
#define TSEQ   2048
#define DMODEL 1024
#define NH     16
#define HDIM   64
#define NKVH   4

typedef __attribute__((ext_vector_type(8))) short short8;
typedef __attribute__((ext_vector_type(8))) _Float16 half8;
typedef __attribute__((ext_vector_type(4))) float f32x4;
typedef __hip_bfloat16 bf16;

// async global->LDS, 16B per lane (linear LDS dest = wave base + lane*16)
__device__ __forceinline__ void gload16(const void* g, void* l) {
    __builtin_amdgcn_global_load_lds(
        (const __attribute__((address_space(1))) uint32_t*)g,
        (__attribute__((address_space(3))) uint32_t*)l, 16, 0, 0);
}

// priority comparator: higher score wins; tie -> lower index wins (matches jax top_k)
__device__ __forceinline__ bool pgt(float as, int ai, float bs, int bi) {
    return (as > bs) || (as == bs && ai < bi);
}

// full bitonic sort across 64 lanes, ascending by priority (validated R6)
__device__ __forceinline__ void bsort(float& s, int& i, int lane) {
#pragma unroll
    for (int k = 2; k <= 64; k <<= 1) {
#pragma unroll
        for (int j = k >> 1; j > 0; j >>= 1) {
            float os = __shfl_xor(s, j, 64);
            int   oi = __shfl_xor(i, j, 64);
            bool lower = (lane & j) == 0;
            bool asc   = (lane & k) == 0;
            bool wmin  = (lower == asc);
            bool takeo = (pgt(s, i, os, oi) == wmin);
            if (takeo) { s = os; i = oi; }
        }
    }
}

// bitonic -> ascending cleanup (6 stages) (validated R6)
__device__ __forceinline__ void bmerge(float& s, int& i, int lane) {
#pragma unroll
    for (int j = 32; j > 0; j >>= 1) {
        float os = __shfl_xor(s, j, 64);
        int   oi = __shfl_xor(i, j, 64);
        bool lower = (lane & j) == 0;
        bool takeo = (pgt(s, i, os, oi) == lower);
        if (takeo) { s = os; i = oi; }
    }
}

// ---- fp32 -> bf16 conversion of x ----
__global__ __launch_bounds__(256) void convert_x(
    const float* __restrict__ x, bf16* __restrict__ cx)
{
    const size_t i0 = (size_t)blockIdx.x * 256 + threadIdx.x;
    const size_t stride = (size_t)gridDim.x * 256;
    for (size_t i = i0; i < 2097152; i += stride) cx[i] = __float2bfloat16(x[i]);
}

// ---- fp32 [R][C] -> bf16 [C][R] tiled transpose-convert (weights, one-shot) ----
__global__ __launch_bounds__(256) void transpose_conv(
    const float* __restrict__ in, bf16* __restrict__ out, int R, int Cc)
{
    __shared__ float tile[32][33];
    const int bx = blockIdx.x * 32;   // col base (n)
    const int by = blockIdx.y * 32;   // row base (k)
    const int tx = threadIdx.x & 31, ty = threadIdx.x >> 5;   // 32 x 8
#pragma unroll
    for (int i = 0; i < 32; i += 8)
        tile[ty + i][tx] = in[(size_t)(by + ty + i) * Cc + bx + tx];
    __syncthreads();
#pragma unroll
    for (int i = 0; i < 32; i += 8)
        out[(size_t)(bx + ty + i) * R + by + tx] = __float2bfloat16(tile[tx][ty + i]);
}

// ---- MFMA GEMM: A[M,K](bf16) @ BT[N,K](bf16)^T + bias, fused epilogue ----
// MODE 0: C[row,col] = acc+bias (fp32)                      (out projection)
// MODE 1: per-row RMSnorm (64-col head tile) * wn * 0.125 -> f16 fh[row,col]  (Q)
// MODE 2: n0<256: k-head RMSnorm * wn -> f16 fh[(kvh,row),d];
//         n0>=256: v -> fp32 vout[(kvh,row),d]               (KV)
// Row's 64 cols live in one wave's 16-lane mm-group x 4 regs -> 4-stage shfl.
// Core loop unchanged from R4 (validated).
template<int MODE>
__global__ __launch_bounds__(256) void gemm_bias(
    const bf16* __restrict__ A, const bf16* __restrict__ BT,
    const float* __restrict__ bias, float* __restrict__ C,
    _Float16* __restrict__ fh, float* __restrict__ vout,
    const float* __restrict__ wn, int M, int N, int K)
{
    __shared__ short As[64][64];   // (m, k-slot-swizzled)  8KB
    __shared__ short Bs[64][64];   // (n, k-slot-swizzled)  8KB
    const int tid = threadIdx.x;
    const int m0 = blockIdx.y * 64, n0 = blockIdx.x * 64;
    const int w = tid >> 6, lane = tid & 63;
    const int q4 = lane >> 4, mm = lane & 15;
    f32x4 acc[4];
#pragma unroll
    for (int nb = 0; nb < 4; ++nb) acc[nb] = (f32x4){0.f, 0.f, 0.f, 0.f};

    const int ar = tid >> 3;                       // 0..31
    const int sslot = (tid & 7) ^ (ar & 7);        // swizzled global k-slot
    const short* Ag = (const short*)A + (size_t)(m0 + ar) * K + sslot * 8;
    const short* Ag2 = (const short*)A + (size_t)(m0 + ar + 32) * K + ((tid & 7) ^ ((ar + 32) & 7)) * 8;
    const short* Bg = (const short*)BT + (size_t)(n0 + ar) * K + sslot * 8;
    const short* Bg2 = (const short*)BT + (size_t)(n0 + ar + 32) * K + ((tid & 7) ^ ((ar + 32) & 7)) * 8;

    const int xm = mm & 7;
    const short* Asf = (const short*)As;
    const short* Bsf = (const short*)Bs;
    const int aoff0 = (w * 16 + mm) * 64 + ((q4 ^ xm)) * 8;
    const int aoff1 = (w * 16 + mm) * 64 + (((4 + q4) ^ xm)) * 8;
    int boff0[4], boff1[4];
#pragma unroll
    for (int nb = 0; nb < 4; ++nb) {
        boff0[nb] = (nb * 16 + mm) * 64 + ((q4 ^ xm)) * 8;
        boff1[nb] = (nb * 16 + mm) * 64 + (((4 + q4) ^ xm)) * 8;
    }

    for (int k0 = 0; k0 < K; k0 += 64) {
        __syncthreads();
        gload16(Ag + k0, &As[ar][(tid & 7) * 8]);
        gload16(Ag2 + k0, &As[ar + 32][(tid & 7) * 8]);
        gload16(Bg + k0, &Bs[ar][(tid & 7) * 8]);
        gload16(Bg2 + k0, &Bs[ar + 32][(tid & 7) * 8]);
        __syncthreads();   // drains vmcnt (compiler emits it before s_barrier)
        short8 af0 = *(const short8*)(Asf + aoff0);
        short8 af1 = *(const short8*)(Asf + aoff1);
#pragma unroll
        for (int nb = 0; nb < 4; ++nb) {
            short8 b0 = *(const short8*)(Bsf + boff0[nb]);
            short8 b1 = *(const short8*)(Bsf + boff1[nb]);
            acc[nb] = __builtin_amdgcn_mfma_f32_16x16x32_bf16(af0, b0, acc[nb], 0, 0, 0);
            acc[nb] = __builtin_amdgcn_mfma_f32_16x16x32_bf16(af1, b1, acc[nb], 0, 0, 0);
        }
    }

    // bias add (all modes)
    float vv[4][4];   // [nb][r]
#pragma unroll
    for (int nb = 0; nb < 4; ++nb)
#pragma unroll
        for (int r = 0; r < 4; ++r)
            vv[nb][r] = acc[nb][r] + bias[n0 + nb * 16 + mm];

    if (MODE == 0) {
#pragma unroll
        for (int nb = 0; nb < 4; ++nb)
#pragma unroll
            for (int r = 0; r < 4; ++r)
                C[(size_t)(m0 + w * 16 + q4 * 4 + r) * N + n0 + nb * 16 + mm] = vv[nb][r];
    } else if (MODE == 1 || (MODE == 2 && n0 < 256)) {
        // per-row RMS norm over the 64-col head tile
#pragma unroll
        for (int r = 0; r < 4; ++r) {
            float ss = 0.f;
#pragma unroll
            for (int nb = 0; nb < 4; ++nb) ss += vv[nb][r] * vv[nb][r];
#pragma unroll
            for (int j = 8; j >= 1; j >>= 1) ss += __shfl_xor(ss, j, 64);
            float rs = 1.0f / sqrtf(ss * (1.0f / 64.0f) + 1e-8f);
            int row = m0 + w * 16 + q4 * 4 + r;
            if (MODE == 1) {
#pragma unroll
                for (int nb = 0; nb < 4; ++nb) {
                    int d = nb * 16 + mm;
                    fh[(size_t)row * DMODEL + n0 + d] =
                        (_Float16)(vv[nb][r] * rs * wn[d] * 0.125f);
                }
            } else {
                int kvh = n0 >> 6;
#pragma unroll
                for (int nb = 0; nb < 4; ++nb) {
                    int d = nb * 16 + mm;
                    fh[((size_t)kvh * TSEQ + row) * HDIM + d] =
                        (_Float16)(vv[nb][r] * rs * wn[d]);
                }
            }
        }
    } else {   // MODE 2, v block
        int kvh = (n0 - 256) >> 6;
#pragma unroll
        for (int r = 0; r < 4; ++r) {
            int row = m0 + w * 16 + q4 * 4 + r;
#pragma unroll
            for (int nb = 0; nb < 4; ++nb)
                vout[((size_t)kvh * TSEQ + row) * HDIM + nb * 16 + mm] = vv[nb][r];
        }
    }
}

// ---- fused MFMA scores + exact top-64 + softmax + V gather ----
// Identical to R9 (validated) except __launch_bounds__(256, 4): 128-VGPR
// budget removes the scratch spills R9's counters showed (WRITE_SIZE 14MB).
__global__ __launch_bounds__(256, 4) void attn_kernel(
    const _Float16* __restrict__ qh, const _Float16* __restrict__ kh,
    const float* __restrict__ vbuf, bf16* __restrict__ ybuf,
    const float* __restrict__ kn_w)
{
    __shared__ float Sg[2][16][68];      // [buf][qrow][key] one chunk
    __shared__ float cbS[16][128];       // per-row candidate scores
    __shared__ int   cbI[16][128];       // per-row candidate indices
    __shared__ int   eminS[4];           // per-wave earliest needed key
    const int tid = threadIdx.x;
    const int w = tid >> 6, lane = tid & 63;
    const int mm = lane & 15, q4 = lane >> 4;
    const int h = 15 - (blockIdx.x >> 7);            // heavy (low-slope) heads first
    const int t0 = (127 - (blockIdx.x & 127)) << 4;  // long rows first within head
    const int kvh = h >> 2;
    const float slope = exp2f(-((float)h) * (8.0f / 15.0f));
    const _Float16* kbase = kh + (size_t)kvh * TSEQ * HDIM;
    const int nch = (t0 + 15) >> 6;

    // max |kn_w| (wave-uniform)
    float kw = fabsf(kn_w[lane]);
#pragma unroll
    for (int j = 32; j > 0; j >>= 1) kw = fmaxf(kw, __shfl_xor(kw, j, 64));
    const float kfac = 8.0f * kw * 1.001f;

    // per-row exact bound B and window for this wave's rows r = 4w+rr
    float Brow[4];
    int em = 0x7fffffff;
#pragma unroll
    for (int rr = 0; rr < 4; ++rr) {
        const int r = 4 * w + rr;
        float qe = (float)qh[(size_t)(t0 + r) * DMODEL + h * HDIM + lane];
        float qs = qe * qe;
#pragma unroll
        for (int j = 32; j > 0; j >>= 1) qs += __shfl_xor(qs, j, 64);
        Brow[rr] = sqrtf(qs) * kfac + 1e-3f;
        float Dw = 2.0f * Brow[rr] / slope + 64.0f;
        int e = (int)floorf((float)(t0 + r) - Dw);
        em = min(em, e);
    }
    if (lane == 0) eminS[w] = em;

    // Q fragments (f16, 1/8 scale folded). A-frag: row=lane&15, k=(lane>>4)*8..+7
    const _Float16* qp = qh + (size_t)(t0 + mm) * DMODEL + h * HDIM + q4 * 8;
    half8 qf0 = *(const half8*)(qp);        // d 0..31
    half8 qf1 = *(const half8*)(qp + 32);   // d 32..63

    // prologue: produce chunk nch into buffer 0 (wave w -> keys w*16..w*16+15)
    {
        const int jb = nch << 6;
        const _Float16* kp = kbase + ((size_t)(jb + w * 16 + mm)) * HDIM + q4 * 8;
        half8 b0 = *(const half8*)(kp);
        half8 b1 = *(const half8*)(kp + 32);
        f32x4 a = __builtin_amdgcn_mfma_f32_16x16x32_f16(
            qf0, b0, (f32x4){0.f, 0.f, 0.f, 0.f}, 0, 0, 0);
        a = __builtin_amdgcn_mfma_f32_16x16x32_f16(qf1, b1, a, 0, 0, 0);
        // C layout: col=lane&15 (key), row=(lane>>4)*4+reg (query)
#pragma unroll
        for (int rr = 0; rr < 4; ++rr)
            Sg[0][q4 * 4 + rr][w * 16 + mm] = a[rr];
    }
    __syncthreads();

    // block-uniform earliest chunk (conservative: min over all rows)
    int em4 = min(min(eminS[0], eminS[1]), min(eminS[2], eminS[3]));
    const int c_min = (em4 > 0) ? (em4 >> 6) : 0;

    float cs[4]; int ci[4]; float thr[4]; int cnt[4];
#pragma unroll
    for (int rr = 0; rr < 4; ++rr) { cs[rr] = -1e30f; ci[rr] = 0; thr[rr] = -1e30f; cnt[rr] = 0; }

    int p = 0;
    for (int c = nch; c >= c_min; --c) {
        // issue next chunk's K loads early (hide L2 latency under merge)
        const int cn = c - 1;
        half8 b0, b1;
        if (cn >= c_min) {
            const _Float16* kp = kbase + ((size_t)((cn << 6) + w * 16 + mm)) * HDIM + q4 * 8;
            b0 = *(const half8*)(kp);
            b1 = *(const half8*)(kp + 32);
        }
        // merge chunk c for this wave's 4 rows
        const int jb = c << 6;
#pragma unroll
        for (int rr = 0; rr < 4; ++rr) {
            const int r = 4 * w + rr;
            // per-row runtime prune (validated): chunk can't reach th
            int dm = (t0 + r - 63) - jb;
            float dmin = (float)(dm > 0 ? dm : 0);
            if (Brow[rr] - slope * dmin < thr[rr]) continue;
            float sr = Sg[p][r][lane];
            int dist = (t0 + r) - (jb + lane);
            float s = sr - slope * (float)dist;
            bool pass = (dist >= 0) && (s >= thr[rr]);
            unsigned long long mk = __ballot(pass);
            if (mk) {
                int rank = __popcll(mk & ((1ull << lane) - 1ull));
                if (pass) { cbS[r][cnt[rr] + rank] = s; cbI[r][cnt[rr] + rank] = jb + lane; }
                cnt[rr] += __popcll(mk);
                if (cnt[rr] >= 64) {
                    float ns = cbS[r][lane];
                    int   ni = cbI[r][lane];
                    bsort(ns, ni, lane);
                    float rsv = __shfl_xor(ns, 63, 64);   // descending view
                    int   riv = __shfl_xor(ni, 63, 64);
                    if (pgt(rsv, riv, cs[rr], ci[rr])) { cs[rr] = rsv; ci[rr] = riv; }
                    bmerge(cs[rr], ci[rr], lane);          // restore ascending
                    thr[rr] = __shfl(cs[rr], 0, 64);
                    int rem = cnt[rr] - 64;
                    float ms = 0.f; int mi = 0;
                    if (lane < rem) { ms = cbS[r][64 + lane]; mi = cbI[r][64 + lane]; }
                    if (lane < rem) { cbS[r][lane] = ms; cbI[r][lane] = mi; }
                    cnt[rr] = rem;
                }
            }
        }
        // produce next chunk into the other buffer
        if (cn >= c_min) {
            f32x4 a = __builtin_amdgcn_mfma_f32_16x16x32_f16(
                qf0, b0, (f32x4){0.f, 0.f, 0.f, 0.f}, 0, 0, 0);
            a = __builtin_amdgcn_mfma_f32_16x16x32_f16(qf1, b1, a, 0, 0, 0);
#pragma unroll
            for (int rr = 0; rr < 4; ++rr)
                Sg[p ^ 1][q4 * 4 + rr][w * 16 + mm] = a[rr];
        }
        p ^= 1;
        __syncthreads();
    }

    // epilogue per row: flush, softmax, V gather, store
    const float* vb = vbuf + (size_t)kvh * TSEQ * HDIM + lane;
#pragma unroll
    for (int rr = 0; rr < 4; ++rr) {
        const int r = 4 * w + rr;
        if (cnt[rr] > 0) {
            float ns = (lane < cnt[rr]) ? cbS[r][lane] : -2e30f;
            int   ni = (lane < cnt[rr]) ? cbI[r][lane] : 0;
            bsort(ns, ni, lane);
            float rsv = __shfl_xor(ns, 63, 64);
            int   riv = __shfl_xor(ni, 63, 64);
            if (pgt(rsv, riv, cs[rr], ci[rr])) { cs[rr] = rsv; ci[rr] = riv; }
            bmerge(cs[rr], ci[rr], lane);
        }
        // softmax over kept 64 (pads -1e30 -> weight 0); max at lane 63
        float msx = __shfl(cs[rr], 63, 64);
        bool valid = cs[rr] > -1e29f;
        float pr = valid ? __expf(cs[rr] - msx) : 0.f;
        float l = pr;
#pragma unroll
        for (int j2 = 32; j2 > 0; j2 >>= 1) l += __shfl_xor(l, j2, 64);
        float wgt = pr / l;
        int widx = valid ? ci[rr] : 0;
        float acc = 0.f;
#pragma unroll 8
        for (int i = 0; i < 64; ++i) {
            float wv = __shfl(wgt, i, 64);
            int  ix = __shfl(widx, i, 64);
            acc += wv * vb[(size_t)ix * HDIM];
        }
        ybuf[(size_t)(t0 + r) * DMODEL + h * HDIM + lane] = __float2bfloat16(acc);
    }
}

extern "C" void kernel_launch(void* const* d_in, const int* in_sizes, int n_in,
                              void* d_out, int out_size, void* d_ws, size_t ws_size,
                              hipStream_t stream)
{
    // d_in order: x, wq, bq, wkv, bkv, wo, bo, qn_w, kn_w  (all fp32)
    const float* x    = (const float*)d_in[0];
    const float* wq   = (const float*)d_in[1];
    const float* bq   = (const float*)d_in[2];
    const float* wkv  = (const float*)d_in[3];
    const float* bkv  = (const float*)d_in[4];
    const float* wo   = (const float*)d_in[5];
    const float* bo   = (const float*)d_in[6];
    const float* qn_w = (const float*)d_in[7];
    const float* kn_w = (const float*)d_in[8];
    char* ws = (char*)d_ws;
    // ws layout (28 MB):
    // cx bf16 4M @0 | cwqT 2M @4M | cwkvT 1M @6M | cwoT 2M @7M |
    // qh f16 4M @9M | kh f16 1M @21M | vbuf fp32 2M @22M |
    // ybuf bf16 4M @24M..28M  (no overlaps; norm fused into GEMM epilogues)
    bf16*      cx    = (bf16*)(ws);
    bf16*      cwqT  = (bf16*)(ws + ((size_t)4  << 20));   // [1024][1024] (n,k)
    bf16*      cwkvT = (bf16*)(ws + ((size_t)6  << 20));   // [512][1024]  (n,k)
    bf16*      cwoT  = (bf16*)(ws + ((size_t)7  << 20));   // [1024][1024] (n,k)
    _Float16*  qh    = (_Float16*)(ws + ((size_t)9  << 20));
    _Float16*  kh    = (_Float16*)(ws + ((size_t)21 << 20));
    float*     vbuf  = (float*)(ws + ((size_t)22 << 20));
    bf16*      ybuf  = (bf16*)(ws + ((size_t)24 << 20));
    float*     out   = (float*)d_out;   // fp32 output

    convert_x<<<1024, 256, 0, stream>>>(x, cx);
    transpose_conv<<<dim3(32, 32), 256, 0, stream>>>(wq, cwqT, 1024, 1024);
    transpose_conv<<<dim3(16, 32), 256, 0, stream>>>(wkv, cwkvT, 1024, 512);
    transpose_conv<<<dim3(32, 32), 256, 0, stream>>>(wo, cwoT, 1024, 1024);
    gemm_bias<1><<<dim3(DMODEL / 64, TSEQ / 64), 256, 0, stream>>>(
        cx, cwqT, bq, nullptr, qh, nullptr, qn_w, TSEQ, DMODEL, DMODEL);
    gemm_bias<2><<<dim3(512 / 64, TSEQ / 64), 256, 0, stream>>>(
        cx, cwkvT, bkv, nullptr, kh, vbuf, kn_w, TSEQ, 512, DMODEL);
    attn_kernel<<<NH * (TSEQ / 16), 256, 0, stream>>>(qh, kh, vbuf, ybuf, kn_w);
    gemm_bias<0><<<dim3(DMODEL / 64, TSEQ / 64), 256, 0, stream>>>(
        ybuf, cwoT, bo, out, nullptr, nullptr, nullptr, TSEQ, DMODEL, DMODEL);
}